// Round 5
// baseline (171.568 us; speedup 1.0000x reference)
//
#include <hip/hip_runtime.h>
#include <hip/hip_bf16.h>

typedef float f32x4 __attribute__((ext_vector_type(4)));
typedef short bf16x8 __attribute__((ext_vector_type(8)));
typedef short s16x4 __attribute__((ext_vector_type(4)));

// Per-wave private LDS slice: a[16][136] ushort (4352 B) + scale[16] f32 (64 B) = 4416 B
// Epilogue overlays a[] as o_f32[8][132] (4224 B) — wave-synchronous reuse, no barriers.
#define WAVE_LDS_BYTES 4416

// Compiler-only memory fence: DS ops are in-order per wave (HW ok); this stops
// TBAA/scheduler reordering across LDS communication boundaries (the R3 bug).
#define LDS_FENCE() do { asm volatile("" ::: "memory"); \
                         __builtin_amdgcn_sched_barrier(0); } while (0)

__device__ __forceinline__ unsigned short f2bf(float f) {
    union { float f; unsigned int u; } v; v.f = f;
    unsigned int u = v.u;
    u += 0x7FFFu + ((u >> 16) & 1u);   // round-to-nearest-even
    return (unsigned short)(u >> 16);
}

// w_eff[o][h] = (w1[o][h] + w2[o][h]) * weight[h], bf16, row-major [128][128]
__global__ void prep_weights_kernel(const float* __restrict__ w1,
                                    const float* __restrict__ w2,
                                    const float* __restrict__ weight,
                                    unsigned short* __restrict__ weff) {
    int idx = blockIdx.x * 256 + threadIdx.x;   // 64 blocks * 256 = 16384
    int h = idx & 127;
    weff[idx] = f2bf((w1[idx] + w2[idx]) * weight[h]);
}

// Zero-barrier design: each wave owns 16 rows end-to-end. No __syncthreads anywhere.
__launch_bounds__(256, 4)
__global__ void fused_rms_gemm_kernel(const float* __restrict__ residual,
                                      const float* __restrict__ attn,
                                      const float* __restrict__ moe,
                                      const unsigned short* __restrict__ weff,
                                      float* __restrict__ combined,
                                      float* __restrict__ nres) {
    __shared__ __align__(16) unsigned char smem[4 * WAVE_LDS_BYTES];

    const int t = threadIdx.x;
    const int w = t >> 6;
    const int l = t & 63;
    unsigned char* wbase = smem + w * WAVE_LDS_BYTES;
    short* a_s16 = (short*)wbase;                         // [16][136] bf16 add-tile
    float* scale = (float*)(wbase + 4352);                // [16]
    float* o_f32 = (float*)wbase;                         // [8][132] epilogue overlay

    const long tile = (long)blockIdx.x * 4 + w;
    const long grow0 = tile * 16;                          // first global row of this wave

    // ---- Phase 1: per-instruction 1KB-contiguous loads/stores (2 rows/iter) ----
    const int half = l >> 5;          // which of the 2 rows this iteration
    const int c4 = l & 31;            // f32x4 slot within a row
#pragma unroll
    for (int i = 0; i < 8; ++i) {
        const int rloc = i * 2 + half;
        const long base = (grow0 + rloc) * 128 + c4 * 4;
        f32x4 a = *(const f32x4*)(residual + base);
        f32x4 b = *(const f32x4*)(attn + base);
        f32x4 m = *(const f32x4*)(moe + base);
        f32x4 s = a + b;
        *(f32x4*)(nres + base) = s + m;
        float p = s.x * s.x + s.y * s.y + s.z * s.z + s.w * s.w;
        s16x4 pk;
        pk.x = (short)f2bf(s.x);
        pk.y = (short)f2bf(s.y);
        pk.z = (short)f2bf(s.z);
        pk.w = (short)f2bf(s.w);
        *(s16x4*)(a_s16 + rloc * 136 + c4 * 4) = pk;
        // row sumsq across the 32 lanes holding this row
        p += __shfl_xor(p, 1);
        p += __shfl_xor(p, 2);
        p += __shfl_xor(p, 4);
        p += __shfl_xor(p, 8);
        p += __shfl_xor(p, 16);
        if (c4 == 0)
            scale[rloc] = rsqrtf(p * (1.0f / 128.0f) + 1e-5f);
    }
    LDS_FENCE();   // all lanes' a_s16/scale writes precede any phase-2 reads

    // ---- Phase 2: D[r][o] = add[r][:] . w_eff[o][:], 16 rows x 128 cols per wave ----
    const int lq = l >> 4;            // k-slot group 0..3
    const int lr = l & 15;            // A-row (frag) / weff-row (B frag) within 16

    bf16x8 afrag[4];
#pragma unroll
    for (int kk = 0; kk < 4; ++kk)
        afrag[kk] = *(const bf16x8*)(a_s16 + lr * 136 + kk * 32 + lq * 8);

    f32x4 acc[8];
#pragma unroll
    for (int n = 0; n < 8; ++n) {
        acc[n] = (f32x4){0.f, 0.f, 0.f, 0.f};
        const unsigned short* wp = weff + (n * 16 + lr) * 128 + lq * 8;
#pragma unroll
        for (int kk = 0; kk < 4; ++kk) {
            bf16x8 bf = *(const bf16x8*)(wp + kk * 32);
            acc[n] = __builtin_amdgcn_mfma_f32_16x16x32_bf16(afrag[kk], bf, acc[n], 0, 0, 0);
        }
    }

    // per-lane scales for C rows lq*4+j (scale[] written in phase 1, fenced above)
    f32x4 sc = *(const f32x4*)(scale + lq * 4);

    LDS_FENCE();   // afrag/scale reads complete before o_f32 overlay writes

    // ---- Phase 3: epilogue, 2 rounds of 8 rows via wave-private LDS transpose ----
    // C/D layout: col = lane&15 (weff row), row = lq*4 + j  [HW-verified]
#pragma unroll
    for (int r2 = 0; r2 < 2; ++r2) {
        if ((lq >> 1) == r2) {
            const int rbase = (lq & 1) * 4;      // row within this 8-row round
#pragma unroll
            for (int n = 0; n < 8; ++n)
#pragma unroll
                for (int j = 0; j < 4; ++j)
                    o_f32[(rbase + j) * 132 + n * 16 + lr] = acc[n][j] * sc[j];
        }
        LDS_FENCE();   // o_f32 writes precede reads
#pragma unroll
        for (int k = 0; k < 4; ++k) {
            const int row = k * 2 + half;        // 2 rows per instruction
            f32x4 v = *(const f32x4*)(o_f32 + row * 132 + c4 * 4);
            *(f32x4*)(combined + (grow0 + r2 * 8 + row) * 128 + c4 * 4) = v;
        }
        LDS_FENCE();   // round-r2 reads precede round-(r2+1) overwrites
    }
}

extern "C" void kernel_launch(void* const* d_in, const int* in_sizes, int n_in,
                              void* d_out, int out_size, void* d_ws, size_t ws_size,
                              hipStream_t stream) {
    const float* residual = (const float*)d_in[0];
    const float* attn     = (const float*)d_in[1];
    const float* moe      = (const float*)d_in[2];
    const float* weight   = (const float*)d_in[3];
    const float* w1       = (const float*)d_in[4];
    const float* w2       = (const float*)d_in[5];

    unsigned short* weff = (unsigned short*)d_ws;  // 32 KB scratch

    const int total = in_sizes[0];                 // B*S*H = 33,554,432
    const int rows = total / 128;                  // 262,144
    float* combined = (float*)d_out;
    float* nres = combined + (size_t)total;

    prep_weights_kernel<<<64, 256, 0, stream>>>(w1, w2, weight, weff);
    // 16 rows per wave, 4 waves per block -> 64 rows per block
    fused_rms_gemm_kernel<<<rows / 64, 256, 0, stream>>>(
        residual, attn, moe, weff, combined, nres);
}

// Round 6
// 158.705 us; speedup vs baseline: 1.0811x; 1.0811x over previous
//
#include <hip/hip_runtime.h>
#include <hip/hip_bf16.h>

typedef float f32x4 __attribute__((ext_vector_type(4)));
typedef short bf16x8 __attribute__((ext_vector_type(8)));
typedef short s16x4 __attribute__((ext_vector_type(4)));

// Per-wave private LDS slice: a[16][136] shorts = 4352 B.
// Epilogue overlays the same region as o_f32[8][132] (4224 B). No scale array.
#define WAVE_LDS_BYTES 4352

// Compiler-only memory fence (DS ops are in-order per wave; lanes lockstep).
#define LDS_FENCE() do { asm volatile("" ::: "memory"); \
                         __builtin_amdgcn_sched_barrier(0); } while (0)

__device__ __forceinline__ unsigned short f2bf(float f) {
    union { float f; unsigned int u; } v; v.f = f;
    unsigned int u = v.u;
    u += 0x7FFFu + ((u >> 16) & 1u);   // round-to-nearest-even
    return (unsigned short)(u >> 16);
}

__device__ __forceinline__ float bf2f(short b) {
    union { unsigned int u; float f; } v;
    v.u = ((unsigned int)(unsigned short)b) << 16;
    return v.f;
}

// w_eff[o][h] = (w1[o][h] + w2[o][h]) * weight[h], bf16, row-major [128][128]
__global__ void prep_weights_kernel(const float* __restrict__ w1,
                                    const float* __restrict__ w2,
                                    const float* __restrict__ weight,
                                    unsigned short* __restrict__ weff) {
    int idx = blockIdx.x * 256 + threadIdx.x;   // 64 blocks * 256 = 16384
    int h = idx & 127;
    weff[idx] = f2bf((w1[idx] + w2[idx]) * weight[h]);
}

// Zero-barrier, wave-private design; VGPR<=64 for 8 waves/SIMD residency.
__launch_bounds__(256, 8)
__global__ void fused_rms_gemm_kernel(const float* __restrict__ residual,
                                      const float* __restrict__ attn,
                                      const float* __restrict__ moe,
                                      const unsigned short* __restrict__ weff,
                                      float* __restrict__ combined,
                                      float* __restrict__ nres) {
    __shared__ __align__(16) unsigned char smem[4 * WAVE_LDS_BYTES];   // 17408 B

    const int t = threadIdx.x;
    const int w = t >> 6;
    const int l = t & 63;
    unsigned char* wbase = smem + w * WAVE_LDS_BYTES;
    short* a_s16 = (short*)wbase;                         // [16][136] bf16 add-tile
    float* o_f32 = (float*)wbase;                         // [8][132] epilogue overlay

    const long grow0 = ((long)blockIdx.x * 4 + w) * 16;   // first global row of wave

    const int half = l >> 5;          // which of 2 rows per iteration
    const int c4 = l & 31;            // f32x4 slot within a row

    // ---- Phase 1: streaming add/store + bf16 pack to LDS; NO cross-lane ops ----
    // Explicit 2-deep pipeline: >=6 loads in flight per wave at all times.
    const long base0 = (grow0 + half) * 128 + c4 * 4;     // iter stride = 256 floats
    f32x4 a0 = *(const f32x4*)(residual + base0);
    f32x4 b0 = *(const f32x4*)(attn + base0);
    f32x4 m0 = *(const f32x4*)(moe + base0);
    f32x4 a1 = *(const f32x4*)(residual + base0 + 256);
    f32x4 b1 = *(const f32x4*)(attn + base0 + 256);
    f32x4 m1 = *(const f32x4*)(moe + base0 + 256);
#pragma unroll
    for (int i = 0; i < 8; ++i) {
        f32x4 a = (i & 1) ? a1 : a0;
        f32x4 b = (i & 1) ? b1 : b0;
        f32x4 m = (i & 1) ? m1 : m0;
        if (i + 2 < 8) {                                  // refill the slot just freed
            const long nb = base0 + (i + 2) * 256;
            if (i & 1) { a1 = *(const f32x4*)(residual + nb);
                         b1 = *(const f32x4*)(attn + nb);
                         m1 = *(const f32x4*)(moe + nb); }
            else       { a0 = *(const f32x4*)(residual + nb);
                         b0 = *(const f32x4*)(attn + nb);
                         m0 = *(const f32x4*)(moe + nb); }
        }
        f32x4 s = a + b;
        *(f32x4*)(nres + base0 + i * 256) = s + m;
        s16x4 pk;
        pk.x = (short)f2bf(s.x);
        pk.y = (short)f2bf(s.y);
        pk.z = (short)f2bf(s.z);
        pk.w = (short)f2bf(s.w);
        *(s16x4*)(a_s16 + (i * 2 + half) * 136 + c4 * 4) = pk;
    }
    LDS_FENCE();   // all lanes' a_s16 writes precede phase-2 reads

    // ---- Phase 2: fragments, sumsq-from-fragments, MFMA ----
    const int lq = l >> 4;            // k-slot group 0..3
    const int lr = l & 15;            // A-row / weff-row within 16

    bf16x8 afrag[4];
#pragma unroll
    for (int kk = 0; kk < 4; ++kk)
        afrag[kk] = *(const bf16x8*)(a_s16 + lr * 136 + kk * 32 + lq * 8);

    // sumsq of row lr: this lane's 32 elems, then combine the 4 lq-quarters.
    float p = 0.f;
#pragma unroll
    for (int kk = 0; kk < 4; ++kk)
#pragma unroll
        for (int e = 0; e < 8; ++e) {
            float f = bf2f(afrag[kk][e]);
            p += f * f;
        }
    p += __shfl_xor(p, 16);
    p += __shfl_xor(p, 32);
    const float scale = rsqrtf(p * (1.0f / 128.0f) + 1e-5f);  // scale of row lr

    f32x4 acc[8];
#pragma unroll
    for (int n = 0; n < 8; ++n) {
        acc[n] = (f32x4){0.f, 0.f, 0.f, 0.f};
        const unsigned short* wp = weff + (n * 16 + lr) * 128 + lq * 8;
#pragma unroll
        for (int kk = 0; kk < 4; ++kk) {
            bf16x8 bf = *(const bf16x8*)(wp + kk * 32);
            acc[n] = __builtin_amdgcn_mfma_f32_16x16x32_bf16(afrag[kk], bf, acc[n], 0, 0, 0);
        }
    }

    // per-lane scales for C rows lq*4+j: fetch from lane (lq*4+j) (its lr == that row)
    float sc[4];
#pragma unroll
    for (int j = 0; j < 4; ++j)
        sc[j] = __shfl(scale, lq * 4 + j);

    LDS_FENCE();   // afrag LDS reads complete before o_f32 overlay writes

    // ---- Phase 3: epilogue, 2 rounds of 8 rows via wave-private LDS transpose ----
    // C/D layout: col = lane&15 (weff row), row = lq*4 + j  [HW-verified]
#pragma unroll
    for (int r2 = 0; r2 < 2; ++r2) {
        if ((lq >> 1) == r2) {
            const int rbase = (lq & 1) * 4;      // row within this 8-row round
#pragma unroll
            for (int n = 0; n < 8; ++n)
#pragma unroll
                for (int j = 0; j < 4; ++j)
                    o_f32[(rbase + j) * 132 + n * 16 + lr] = acc[n][j] * sc[j];
        }
        LDS_FENCE();   // o_f32 writes precede reads
#pragma unroll
        for (int k = 0; k < 4; ++k) {
            const int row = k * 2 + half;        // 2 rows per instruction (1KB)
            f32x4 v = *(const f32x4*)(o_f32 + row * 132 + c4 * 4);
            *(f32x4*)(combined + (grow0 + r2 * 8 + row) * 128 + c4 * 4) = v;
        }
        LDS_FENCE();   // round-r2 reads precede round-(r2+1) overwrites
    }
}

extern "C" void kernel_launch(void* const* d_in, const int* in_sizes, int n_in,
                              void* d_out, int out_size, void* d_ws, size_t ws_size,
                              hipStream_t stream) {
    const float* residual = (const float*)d_in[0];
    const float* attn     = (const float*)d_in[1];
    const float* moe      = (const float*)d_in[2];
    const float* weight   = (const float*)d_in[3];
    const float* w1       = (const float*)d_in[4];
    const float* w2       = (const float*)d_in[5];

    unsigned short* weff = (unsigned short*)d_ws;  // 32 KB scratch

    const int total = in_sizes[0];                 // B*S*H = 33,554,432
    const int rows = total / 128;                  // 262,144
    float* combined = (float*)d_out;
    float* nres = combined + (size_t)total;

    prep_weights_kernel<<<64, 256, 0, stream>>>(w1, w2, weight, weff);
    // 16 rows per wave, 4 waves per block -> 64 rows per block
    fused_rms_gemm_kernel<<<rows / 64, 256, 0, stream>>>(
        residual, attn, moe, weff, combined, nres);
}